// Round 16
// baseline (38.672 us; speedup 1.0000x reference)
//
#include <hip/hip_runtime.h>
#include <hip/hip_bf16.h>

#define TV    512
#define TL    64
#define D_    512
#define BKT   64
#define VROWS 128
#define NCHUNK (TV/VROWS)   // 4
#define NKT   (D_/BKT)      // 8

typedef __attribute__((ext_vector_type(8))) short bf16x8;
typedef __attribute__((ext_vector_type(4))) float f32x4;

__global__ __launch_bounds__(1024, 8) void chamfer_main(
    const float* __restrict__ vf, const float* __restrict__ lf,
    const float* __restrict__ mv, const float* __restrict__ ml,
    float* __restrict__ pcol, float* __restrict__ psum)
{
  // NO XCD swizzle: consecutive chunks round-robin across XCDs, spreading
  // each batch's V-stream over all 8 L3 ports (R16 experiment).
  const int lin   = blockIdx.x;          // 0..511
  const int chunk = lin & 3;
  const int b     = lin >> 2;            // 0..127

  const int t     = threadIdx.x;         // 0..1023
  const int w     = t >> 6;              // 0..15
  const int lane  = t & 63;
  const int g     = lane >> 4;
  const int c15   = lane & 15;
  const int rt    = w >> 1;              // row-tile 0..7 (16 rows)
  const int ch    = w & 1;               // col-half 0..1 (32 cols)
  const int srow  = t >> 3;              // staging row 0..127
  const int skc   = t & 7;               // staging k-chunk (8 floats)

  // single-buffered swizzled bf16 tiles; R4 transient staging idiom
  __shared__ __align__(16) short lv[VROWS * BKT];  // 16 KiB
  __shared__ __align__(16) short ll[TL * BKT];     // 8 KiB
  __shared__ float normv_s[VROWS];
  __shared__ float norml_s[TL];
  __shared__ float mvs[VROWS];
  __shared__ float mls[TL];
  __shared__ float rowp[16][16];
  __shared__ float colp[16][32];
  __shared__ float wsum[2];

  const int v0 = chunk * VROWS;
  const float* vbase = vf + ((size_t)b * TV + v0) * D_;
  const float* lbase = lf + (size_t)b * TL * D_;
  const float* vsrc = vbase + (size_t)srow * D_ + skc * 8;
  const float* lsrc = lbase + (size_t)srow * D_ + skc * 8;   // valid when t<512

  if (t < VROWS)                mvs[t]        = mv[(size_t)b * TV + v0 + t];
  else if (t < VROWS + TL)      mls[t - VROWS] = ml[(size_t)b * TL + (t - VROWS)];

  f32x4 acc[2];
  acc[0] = (f32x4){0.f, 0.f, 0.f, 0.f};
  acc[1] = (f32x4){0.f, 0.f, 0.f, 0.f};

  float nvacc = 0.f;   // V row srow partial (8 lanes share a row)
  float nlacc = 0.f;   // L row srow partial (t<512 only)

  const int soff = (srow * 128 + skc * 16) ^ ((srow & 7) << 4);
  const int loff = ((srow & 63) * 128 + skc * 16) ^ ((srow & 7) << 4);

  for (int kt = 0; kt < NKT; ++kt) {
    // ---- stage V 128x64 + L 64x64 (bf16, swizzled), fully transient ----
    {
      const float4* sv_ = (const float4*)(vsrc + kt * BKT);
      float4 a = sv_[0], bq = sv_[1];
      nvacc += a.x*a.x + a.y*a.y + a.z*a.z + a.w*a.w
             + bq.x*bq.x + bq.y*bq.y + bq.z*bq.z + bq.w*bq.w;
      union { bf16x8 v8; __hip_bfloat162 h[4]; } u;
      u.h[0] = __float22bfloat162_rn(make_float2(a.x, a.y));
      u.h[1] = __float22bfloat162_rn(make_float2(a.z, a.w));
      u.h[2] = __float22bfloat162_rn(make_float2(bq.x, bq.y));
      u.h[3] = __float22bfloat162_rn(make_float2(bq.z, bq.w));
      *(bf16x8*)((char*)lv + soff) = u.v8;
    }
    if (t < 512) {
      const float4* sl_ = (const float4*)(lsrc + kt * BKT);
      float4 c = sl_[0], dq = sl_[1];
      nlacc += c.x*c.x + c.y*c.y + c.z*c.z + c.w*c.w
             + dq.x*dq.x + dq.y*dq.y + dq.z*dq.z + dq.w*dq.w;
      union { bf16x8 v8; __hip_bfloat162 h[4]; } u2;
      u2.h[0] = __float22bfloat162_rn(make_float2(c.x, c.y));
      u2.h[1] = __float22bfloat162_rn(make_float2(c.z, c.w));
      u2.h[2] = __float22bfloat162_rn(make_float2(dq.x, dq.y));
      u2.h[3] = __float22bfloat162_rn(make_float2(dq.z, dq.w));
      *(bf16x8*)((char*)ll + loff) = u2.v8;
    }
    __syncthreads();
    // ---- MFMA: wave (rt, ch); 2 k-steps of 32 ----
    #pragma unroll
    for (int ks = 0; ks < 2; ks++) {
      bf16x8 afr, bfr[2];
      {
        int row = rt * 16 + c15;
        int off = (row * 128 + ks * 64 + g * 16) ^ ((row & 7) << 4);
        afr = *(const bf16x8*)((const char*)lv + off);
      }
      #pragma unroll
      for (int n = 0; n < 2; n++) {
        int row = ch * 32 + n * 16 + c15;
        int off = (row * 128 + ks * 64 + g * 16) ^ ((row & 7) << 4);
        bfr[n] = *(const bf16x8*)((const char*)ll + off);
      }
      #pragma unroll
      for (int n = 0; n < 2; n++)
        acc[n] = __builtin_amdgcn_mfma_f32_16x16x32_bf16(afr, bfr[n], acc[n], 0, 0, 0);
    }
    __syncthreads();
  }

  // ---- row-norm reductions (8 consecutive lanes share a staged row) ----
  {
    float s = nvacc;
    s += __shfl_xor(s, 1); s += __shfl_xor(s, 2); s += __shfl_xor(s, 4);
    if ((t & 7) == 0) normv_s[srow] = s;
  }
  if (t < 512) {
    float s2 = nlacc;
    s2 += __shfl_xor(s2, 1); s2 += __shfl_xor(s2, 2); s2 += __shfl_xor(s2, 4);
    if ((t & 7) == 0) norml_s[srow] = s2;
  }
  __syncthreads();

  // ---- epilogue: pd + masking, row/col mins ----
  const float BIG = 3.0e38f;
  float pdv[2][4];   // [n][j]
  #pragma unroll
  for (int n = 0; n < 2; n++)
    #pragma unroll
    for (int j = 0; j < 4; j++) {
      int row = rt * 16 + g * 4 + j;
      int col = ch * 32 + n * 16 + c15;
      float pd = normv_s[row] + norml_s[col] - 2.0f * acc[n][j];
      bool valid = (mvs[row] != 0.f) && (mls[col] != 0.f);
      pdv[n][j] = valid ? pd : BIG;
    }

  // per-wave row-min over its 32 cols
  #pragma unroll
  for (int j = 0; j < 4; j++) {
    float rm = fminf(pdv[0][j], pdv[1][j]);
    rm = fminf(rm, __shfl_xor(rm, 1));
    rm = fminf(rm, __shfl_xor(rm, 2));
    rm = fminf(rm, __shfl_xor(rm, 4));
    rm = fminf(rm, __shfl_xor(rm, 8));
    if (c15 == 0) rowp[w][g * 4 + j] = rm;
  }
  // per-wave col-min over its 16 rows
  #pragma unroll
  for (int n = 0; n < 2; n++) {
    float cm = fminf(fminf(pdv[n][0], pdv[n][1]),
                     fminf(pdv[n][2], pdv[n][3]));
    cm = fminf(cm, __shfl_xor(cm, 16));
    cm = fminf(cm, __shfl_xor(cm, 32));
    if (g == 0) colp[w][n * 16 + c15] = cm;
  }
  __syncthreads();

  if (t < VROWS) {
    // rows: combine the two col-halves; masked sums (waves 0,1)
    int row = t;
    float rm = fminf(rowp[(row >> 4) * 2 + 0][row & 15],
                     rowp[(row >> 4) * 2 + 1][row & 15]);
    float sl = (mvs[row] != 0.f) ? rm : 0.f;
    #pragma unroll
    for (int s = 1; s < 64; s <<= 1) sl += __shfl_xor(sl, s);
    if (lane == 0) wsum[w] = sl;   // w = 0 or 1 here
  }
  __syncthreads();
  if (t == 0)
    psum[(size_t)b * NCHUNK + chunk] = wsum[0] + wsum[1];
  if (t < TL) {
    int c = t, chh = c >> 5, lc = c & 31;
    float cm = colp[0 * 2 + chh][lc];
    #pragma unroll
    for (int r = 1; r < 8; r++) cm = fminf(cm, colp[r * 2 + chh][lc]);
    pcol[((size_t)b * NCHUNK + chunk) * TL + c] = cm;
  }
}

__global__ __launch_bounds__(64) void chamfer_fin(
    const float* __restrict__ pcol, const float* __restrict__ psum,
    const float* __restrict__ mv, const float* __restrict__ ml,
    float* __restrict__ out)
{
  int b = blockIdx.x;
  int l = threadIdx.x;
  float cm = pcol[((size_t)b * NCHUNK + 0) * 64 + l];
  #pragma unroll
  for (int i = 1; i < NCHUNK; i++)
    cm = fminf(cm, pcol[((size_t)b * NCHUNK + i) * 64 + l]);
  float mlv = ml[(size_t)b * 64 + l];
  float sl = (mlv != 0.f) ? cm : 0.f;
  float nl = mlv;
  float nv = 0.f;
  #pragma unroll
  for (int i = 0; i < 8; i++) nv += mv[(size_t)b * 512 + l * 8 + i];
  float sv = (l < NCHUNK) ? psum[(size_t)b * NCHUNK + l] : 0.f;
  #pragma unroll
  for (int s = 1; s < 64; s <<= 1) {
    sl += __shfl_xor(sl, s);
    nl += __shfl_xor(nl, s);
    nv += __shfl_xor(nv, s);
    sv += __shfl_xor(sv, s);
  }
  if (l == 0) out[b] = sl / nl + sv / nv;
}

extern "C" void kernel_launch(void* const* d_in, const int* in_sizes, int n_in,
                              void* d_out, int out_size, void* d_ws, size_t ws_size,
                              hipStream_t stream) {
  const float* vf = (const float*)d_in[0];
  const float* lf = (const float*)d_in[1];
  const float* mv = (const float*)d_in[2];
  const float* ml = (const float*)d_in[3];
  float* out  = (float*)d_out;
  float* pcol = (float*)d_ws;                       // [128][4][64]
  float* psum = pcol + 128 * NCHUNK * 64;           // [128][4]
  chamfer_main<<<128 * NCHUNK, 1024, 0, stream>>>(vf, lf, mv, ml, pcol, psum);
  chamfer_fin<<<128, 64, 0, stream>>>(pcol, psum, mv, ml, out);
}

// Round 17
// 32.262 us; speedup vs baseline: 1.1987x; 1.1987x over previous
//
#include <hip/hip_runtime.h>
#include <hip/hip_bf16.h>

#define TV    512
#define TL    64
#define D_    512
#define BKT   64
#define VROWS 128
#define NCHUNK (TV/VROWS)   // 4
#define NKT   (D_/BKT)      // 8

typedef __attribute__((ext_vector_type(8))) short bf16x8;
typedef __attribute__((ext_vector_type(4))) float f32x4;

__global__ __launch_bounds__(1024, 8) void chamfer_main(
    const float* __restrict__ vf, const float* __restrict__ lf,
    const float* __restrict__ mv, const float* __restrict__ ml,
    float* __restrict__ pcol, float* __restrict__ psum)
{
  // XCD-aware decode: all 4 chunks of a batch land on the same XCD.
  const int lin   = blockIdx.x;          // 0..511
  const int xcd   = lin & 7;
  const int kk    = lin >> 3;            // 0..63
  const int chunk = kk & 3;
  const int b     = ((kk >> 2) << 3) | xcd;   // bijective over 0..127

  const int t     = threadIdx.x;         // 0..1023
  const int w     = t >> 6;              // 0..15
  const int lane  = t & 63;
  const int g     = lane >> 4;
  const int c15   = lane & 15;
  const int rt    = w >> 1;              // row-tile 0..7 (16 rows)
  const int ch    = w & 1;               // col-half 0..1 (32 cols)
  const int srow  = t >> 3;              // staging row 0..127
  const int skc   = t & 7;               // staging k-chunk (8 floats)

  // single-buffered swizzled bf16 tiles; R4 transient staging idiom
  __shared__ __align__(16) short lv[VROWS * BKT];  // 16 KiB
  __shared__ __align__(16) short ll[TL * BKT];     // 8 KiB
  __shared__ float normv_s[VROWS];
  __shared__ float norml_s[TL];
  __shared__ float mvs[VROWS];
  __shared__ float mls[TL];
  __shared__ float rowp[16][16];
  __shared__ float colp[16][32];
  __shared__ float wsum[2];

  const int v0 = chunk * VROWS;
  const float* vbase = vf + ((size_t)b * TV + v0) * D_;
  const float* lbase = lf + (size_t)b * TL * D_;
  const float* vsrc = vbase + (size_t)srow * D_ + skc * 8;
  const float* lsrc = lbase + (size_t)srow * D_ + skc * 8;   // valid when t<512

  if (t < VROWS)                mvs[t]        = mv[(size_t)b * TV + v0 + t];
  else if (t < VROWS + TL)      mls[t - VROWS] = ml[(size_t)b * TL + (t - VROWS)];

  f32x4 acc[2];
  acc[0] = (f32x4){0.f, 0.f, 0.f, 0.f};
  acc[1] = (f32x4){0.f, 0.f, 0.f, 0.f};

  float nvacc = 0.f;   // V row srow partial (8 lanes share a row)
  float nlacc = 0.f;   // L row srow partial (t<512 only)

  const int soff = (srow * 128 + skc * 16) ^ ((srow & 7) << 4);
  const int loff = ((srow & 63) * 128 + skc * 16) ^ ((srow & 7) << 4);

  for (int kt = 0; kt < NKT; ++kt) {
    // ---- stage V 128x64 + L 64x64 (bf16, swizzled), fully transient ----
    {
      const float4* sv_ = (const float4*)(vsrc + kt * BKT);
      float4 a = sv_[0], bq = sv_[1];
      nvacc += a.x*a.x + a.y*a.y + a.z*a.z + a.w*a.w
             + bq.x*bq.x + bq.y*bq.y + bq.z*bq.z + bq.w*bq.w;
      union { bf16x8 v8; __hip_bfloat162 h[4]; } u;
      u.h[0] = __float22bfloat162_rn(make_float2(a.x, a.y));
      u.h[1] = __float22bfloat162_rn(make_float2(a.z, a.w));
      u.h[2] = __float22bfloat162_rn(make_float2(bq.x, bq.y));
      u.h[3] = __float22bfloat162_rn(make_float2(bq.z, bq.w));
      *(bf16x8*)((char*)lv + soff) = u.v8;
    }
    if (t < 512) {
      const float4* sl_ = (const float4*)(lsrc + kt * BKT);
      float4 c = sl_[0], dq = sl_[1];
      nlacc += c.x*c.x + c.y*c.y + c.z*c.z + c.w*c.w
             + dq.x*dq.x + dq.y*dq.y + dq.z*dq.z + dq.w*dq.w;
      union { bf16x8 v8; __hip_bfloat162 h[4]; } u2;
      u2.h[0] = __float22bfloat162_rn(make_float2(c.x, c.y));
      u2.h[1] = __float22bfloat162_rn(make_float2(c.z, c.w));
      u2.h[2] = __float22bfloat162_rn(make_float2(dq.x, dq.y));
      u2.h[3] = __float22bfloat162_rn(make_float2(dq.z, dq.w));
      *(bf16x8*)((char*)ll + loff) = u2.v8;
    }
    __syncthreads();
    // ---- MFMA: wave (rt, ch); 2 k-steps of 32 ----
    #pragma unroll
    for (int ks = 0; ks < 2; ks++) {
      bf16x8 afr, bfr[2];
      {
        int row = rt * 16 + c15;
        int off = (row * 128 + ks * 64 + g * 16) ^ ((row & 7) << 4);
        afr = *(const bf16x8*)((const char*)lv + off);
      }
      #pragma unroll
      for (int n = 0; n < 2; n++) {
        int row = ch * 32 + n * 16 + c15;
        int off = (row * 128 + ks * 64 + g * 16) ^ ((row & 7) << 4);
        bfr[n] = *(const bf16x8*)((const char*)ll + off);
      }
      #pragma unroll
      for (int n = 0; n < 2; n++)
        acc[n] = __builtin_amdgcn_mfma_f32_16x16x32_bf16(afr, bfr[n], acc[n], 0, 0, 0);
    }
    __syncthreads();
  }

  // ---- row-norm reductions (8 consecutive lanes share a staged row) ----
  {
    float s = nvacc;
    s += __shfl_xor(s, 1); s += __shfl_xor(s, 2); s += __shfl_xor(s, 4);
    if ((t & 7) == 0) normv_s[srow] = s;
  }
  if (t < 512) {
    float s2 = nlacc;
    s2 += __shfl_xor(s2, 1); s2 += __shfl_xor(s2, 2); s2 += __shfl_xor(s2, 4);
    if ((t & 7) == 0) norml_s[srow] = s2;
  }
  __syncthreads();

  // ---- epilogue: pd + masking, row/col mins ----
  const float BIG = 3.0e38f;
  float pdv[2][4];   // [n][j]
  #pragma unroll
  for (int n = 0; n < 2; n++)
    #pragma unroll
    for (int j = 0; j < 4; j++) {
      int row = rt * 16 + g * 4 + j;
      int col = ch * 32 + n * 16 + c15;
      float pd = normv_s[row] + norml_s[col] - 2.0f * acc[n][j];
      bool valid = (mvs[row] != 0.f) && (mls[col] != 0.f);
      pdv[n][j] = valid ? pd : BIG;
    }

  // per-wave row-min over its 32 cols
  #pragma unroll
  for (int j = 0; j < 4; j++) {
    float rm = fminf(pdv[0][j], pdv[1][j]);
    rm = fminf(rm, __shfl_xor(rm, 1));
    rm = fminf(rm, __shfl_xor(rm, 2));
    rm = fminf(rm, __shfl_xor(rm, 4));
    rm = fminf(rm, __shfl_xor(rm, 8));
    if (c15 == 0) rowp[w][g * 4 + j] = rm;
  }
  // per-wave col-min over its 16 rows
  #pragma unroll
  for (int n = 0; n < 2; n++) {
    float cm = fminf(fminf(pdv[n][0], pdv[n][1]),
                     fminf(pdv[n][2], pdv[n][3]));
    cm = fminf(cm, __shfl_xor(cm, 16));
    cm = fminf(cm, __shfl_xor(cm, 32));
    if (g == 0) colp[w][n * 16 + c15] = cm;
  }
  __syncthreads();

  if (t < VROWS) {
    // rows: combine the two col-halves; masked sums (waves 0,1)
    int row = t;
    float rm = fminf(rowp[(row >> 4) * 2 + 0][row & 15],
                     rowp[(row >> 4) * 2 + 1][row & 15]);
    float sl = (mvs[row] != 0.f) ? rm : 0.f;
    #pragma unroll
    for (int s = 1; s < 64; s <<= 1) sl += __shfl_xor(sl, s);
    if (lane == 0) wsum[w] = sl;   // w = 0 or 1 here
  }
  __syncthreads();
  if (t == 0)
    psum[(size_t)b * NCHUNK + chunk] = wsum[0] + wsum[1];
  if (t < TL) {
    int c = t, chh = c >> 5, lc = c & 31;
    float cm = colp[0 * 2 + chh][lc];
    #pragma unroll
    for (int r = 1; r < 8; r++) cm = fminf(cm, colp[r * 2 + chh][lc]);
    pcol[((size_t)b * NCHUNK + chunk) * TL + c] = cm;
  }
}

__global__ __launch_bounds__(64) void chamfer_fin(
    const float* __restrict__ pcol, const float* __restrict__ psum,
    const float* __restrict__ mv, const float* __restrict__ ml,
    float* __restrict__ out)
{
  int b = blockIdx.x;
  int l = threadIdx.x;
  float cm = pcol[((size_t)b * NCHUNK + 0) * 64 + l];
  #pragma unroll
  for (int i = 1; i < NCHUNK; i++)
    cm = fminf(cm, pcol[((size_t)b * NCHUNK + i) * 64 + l]);
  float mlv = ml[(size_t)b * 64 + l];
  float sl = (mlv != 0.f) ? cm : 0.f;
  float nl = mlv;
  float nv = 0.f;
  #pragma unroll
  for (int i = 0; i < 8; i++) nv += mv[(size_t)b * 512 + l * 8 + i];
  float sv = (l < NCHUNK) ? psum[(size_t)b * NCHUNK + l] : 0.f;
  #pragma unroll
  for (int s = 1; s < 64; s <<= 1) {
    sl += __shfl_xor(sl, s);
    nl += __shfl_xor(nl, s);
    nv += __shfl_xor(nv, s);
    sv += __shfl_xor(sv, s);
  }
  if (l == 0) out[b] = sl / nl + sv / nv;
}

extern "C" void kernel_launch(void* const* d_in, const int* in_sizes, int n_in,
                              void* d_out, int out_size, void* d_ws, size_t ws_size,
                              hipStream_t stream) {
  const float* vf = (const float*)d_in[0];
  const float* lf = (const float*)d_in[1];
  const float* mv = (const float*)d_in[2];
  const float* ml = (const float*)d_in[3];
  float* out  = (float*)d_out;
  float* pcol = (float*)d_ws;                       // [128][4][64]
  float* psum = pcol + 128 * NCHUNK * 64;           // [128][4]
  chamfer_main<<<128 * NCHUNK, 1024, 0, stream>>>(vf, lf, mv, ml, pcol, psum);
  chamfer_fin<<<128, 64, 0, stream>>>(pcol, psum, mv, ml, out);
}